// Round 7
// baseline (731.016 us; speedup 1.0000x reference)
//
#include <hip/hip_runtime.h>
#include <math.h>

#define NN 100000      // nodes
#define DIN 128        // input features
#define NC 10          // classes
#define PAD 16         // node-array row stride (floats) -> 64B rows (1 cache line)
#define MPAD 10        // msg row stride (floats) -> 40B rows (8B aligned)
#define MU 800000      // undirected edge pairs
#define EE (2 * MU)    // directed edges

#define NODE_BLOCKS ((NN + 255) / 256)   // 391
#define PAIR_BLOCKS ((MU + 255) / 256)   // 3125
#define EDGE_BLOCKS ((EE + 255) / 256)   // 6250

// ---------- load/store 10 floats, 16B-aligned row (node arrays) ------------
__device__ __forceinline__ void load_row16(const float* __restrict__ p, float* r) {
    float4 v0 = *reinterpret_cast<const float4*>(p);
    float4 v1 = *reinterpret_cast<const float4*>(p + 4);
    float2 v2 = *reinterpret_cast<const float2*>(p + 8);
    r[0]=v0.x; r[1]=v0.y; r[2]=v0.z; r[3]=v0.w;
    r[4]=v1.x; r[5]=v1.y; r[6]=v1.z; r[7]=v1.w;
    r[8]=v2.x; r[9]=v2.y;
}
// ---------- load/store 10 floats, 8B-aligned row (msg array) ---------------
__device__ __forceinline__ void load_row8(const float* __restrict__ p, float* r) {
#pragma unroll
    for (int i = 0; i < 5; ++i) {
        float2 v = *reinterpret_cast<const float2*>(p + 2 * i);
        r[2 * i] = v.x; r[2 * i + 1] = v.y;
    }
}
__device__ __forceinline__ void store_row8(float* __restrict__ p, const float* r) {
#pragma unroll
    for (int i = 0; i < 5; ++i)
        *reinterpret_cast<float2*>(p + 2 * i) = make_float2(r[2 * i], r[2 * i + 1]);
}

// ---------- shared device bodies -------------------------------------------
__device__ __forceinline__ void transform_body(
    int n, int tid, const float* __restrict__ x, const float* __restrict__ W,
    const float* __restrict__ b, float* __restrict__ log_b0,
    float* __restrict__ log_b, float* Ws, float* bs)
{
    for (int i = tid; i < DIN * NC; i += 256) Ws[i] = W[i];
    if (tid < NC) bs[tid] = b[tid];
    __syncthreads();
    if (n >= NN) return;

    float acc[NC];
#pragma unroll
    for (int c = 0; c < NC; ++c) acc[c] = bs[c];

    const float4* xr = reinterpret_cast<const float4*>(x + (size_t)n * DIN);
#pragma unroll 4
    for (int k4 = 0; k4 < DIN / 4; ++k4) {
        float4 xv = xr[k4];
#pragma unroll
        for (int c = 0; c < NC; ++c) {
            acc[c] = fmaf(xv.x, Ws[(k4 * 4 + 0) * NC + c], acc[c]);
            acc[c] = fmaf(xv.y, Ws[(k4 * 4 + 1) * NC + c], acc[c]);
            acc[c] = fmaf(xv.z, Ws[(k4 * 4 + 2) * NC + c], acc[c]);
            acc[c] = fmaf(xv.w, Ws[(k4 * 4 + 3) * NC + c], acc[c]);
        }
    }
    float m = acc[0];
#pragma unroll
    for (int c = 1; c < NC; ++c) m = fmaxf(m, acc[c]);
    float s = 0.f;
#pragma unroll
    for (int c = 0; c < NC; ++c) s += __expf(acc[c] - m);
    float lse = m + __logf(s);

    size_t o = (size_t)n * PAD;
#pragma unroll
    for (int c = 0; c < NC; ++c) {
        float v = acc[c] - lse;
        log_b0[o + c] = v;
        log_b [o + c] = v;
    }
}

template <int FIRST>
__device__ __forceinline__ void edge_body(
    int e, const int* __restrict__ ei, const float* __restrict__ log_b,
    float* __restrict__ msg, const float* Hs)
{
    int u = ei[e];          // directed edge e:    u -> v
    int v = ei[EE + e];     // directed edge e+MU: v -> u

    float* muv = msg + (size_t)e * MPAD;
    float* mvu = msg + (size_t)(e + MU) * MPAD;

    float lbu[NC], lbv[NC];
    load_row16(log_b + (size_t)u * PAD, lbu);
    load_row16(log_b + (size_t)v * PAD, lbv);

    float v_uv[NC], v_vu[NC];
    if (FIRST) {
#pragma unroll
        for (int c = 0; c < NC; ++c) { v_uv[c] = lbu[c]; v_vu[c] = lbv[c]; }
    } else {
        float mo_uv[NC], mo_vu[NC];
        load_row8(muv, mo_uv);
        load_row8(mvu, mo_vu);
#pragma unroll
        for (int c = 0; c < NC; ++c) {
            v_uv[c] = lbu[c] - mo_vu[c];   // u->v subtracts reverse (v->u)
            v_vu[c] = lbv[c] - mo_uv[c];
        }
    }

    float m_uv = v_uv[0], m_vu = v_vu[0];
#pragma unroll
    for (int c = 1; c < NC; ++c) {
        m_uv = fmaxf(m_uv, v_uv[c]);
        m_vu = fmaxf(m_vu, v_vu[c]);
    }
    float p_uv[NC], p_vu[NC];
#pragma unroll
    for (int c = 0; c < NC; ++c) {
        p_uv[c] = __expf(v_uv[c] - m_uv);
        p_vu[c] = __expf(v_vu[c] - m_vu);
    }
    float q_uv[NC], q_vu[NC];
#pragma unroll
    for (int c = 0; c < NC; ++c) { q_uv[c] = 0.f; q_vu[c] = 0.f; }
#pragma unroll
    for (int c1 = 0; c1 < NC; ++c1) {
        float a = p_uv[c1], bb = p_vu[c1];
#pragma unroll
        for (int c2 = 0; c2 < NC; ++c2) {
            float h = Hs[c1 * NC + c2];      // shared by both directions (CSE)
            q_uv[c2] = fmaf(a, h, q_uv[c2]);
            q_vu[c2] = fmaf(bb, h, q_vu[c2]);
        }
    }
    float Q_uv = 0.f, Q_vu = 0.f;
#pragma unroll
    for (int c = 0; c < NC; ++c) { Q_uv += q_uv[c]; Q_vu += q_vu[c]; }
    float lQ_uv = __logf(Q_uv), lQ_vu = __logf(Q_vu);

    float nm_uv[NC], nm_vu[NC];
#pragma unroll
    for (int c = 0; c < NC; ++c) {
        nm_uv[c] = __logf(q_uv[c]) - lQ_uv;
        nm_vu[c] = __logf(q_vu[c]) - lQ_vu;
    }
    store_row8(muv, nm_uv);
    store_row8(mvu, nm_vu);
}

__device__ __forceinline__ void stage_H(const float* __restrict__ T, float* Hs, int tid)
{
    if (tid < NC * NC) {
        int i = tid / NC, j = tid % NC;
        float d2 = 0.f;
#pragma unroll
        for (int k = 0; k < NC; ++k) {
            float d = T[i * NC + k] - T[j * NC + k];
            d2 = fmaf(d, d, d2);
        }
        Hs[tid] = __expf(-d2);
    }
    __syncthreads();
}

// ---------------------------------------------------------------------------
// K_A: blocks [0, NODE_BLOCKS) run transform; the rest run count.
// Independent work, disjoint outputs; deg pre-zeroed by hipMemsetAsync.
// ---------------------------------------------------------------------------
__global__ __launch_bounds__(256) void k_transform_count(
    const float* __restrict__ x, const float* __restrict__ W,
    const float* __restrict__ b, const int* __restrict__ ei,
    float* __restrict__ log_b0, float* __restrict__ log_b,
    int* __restrict__ deg)
{
    __shared__ float Ws[DIN * NC];
    __shared__ float bs[NC];
    if (blockIdx.x < NODE_BLOCKS) {
        int n = blockIdx.x * 256 + threadIdx.x;
        transform_body(n, threadIdx.x, x, W, b, log_b0, log_b, Ws, bs);
    } else {
        int e = (blockIdx.x - NODE_BLOCKS) * 256 + threadIdx.x;
        if (e < EE) atomicAdd(&deg[ei[EE + e]], 1);   // dst of directed edge e
    }
}

// ---------------------------------------------------------------------------
// scans
// ---------------------------------------------------------------------------
__global__ __launch_bounds__(256) void scan1_kernel(
    const int* __restrict__ deg, int* __restrict__ row, int* __restrict__ bsum)
{
    __shared__ int tmp[256];
    int t = threadIdx.x;
    int n = blockIdx.x * 256 + t;
    int val = (n < NN) ? deg[n] : 0;
    tmp[t] = val;
    __syncthreads();
#pragma unroll
    for (int off = 1; off < 256; off <<= 1) {
        int v = (t >= off) ? tmp[t - off] : 0;
        __syncthreads();
        tmp[t] += v;
        __syncthreads();
    }
    if (n < NN) row[n] = tmp[t] - val;      // exclusive within block
    if (t == 255) bsum[blockIdx.x] = tmp[t];
}

__global__ __launch_bounds__(512) void scan2_kernel(int* __restrict__ bsum, int nb)
{
    __shared__ int tmp[512];
    int t = threadIdx.x;
    tmp[t] = (t < nb) ? bsum[t] : 0;
    __syncthreads();
#pragma unroll
    for (int off = 1; off < 512; off <<= 1) {
        int v = (t >= off) ? tmp[t - off] : 0;
        __syncthreads();
        tmp[t] += v;
        __syncthreads();
    }
    if (t < nb) bsum[t] = (t == 0) ? 0 : tmp[t - 1];   // exclusive
}

// row[n] += bsum[block]; cursor[n] = row[n]; row[NN] = EE
__global__ __launch_bounds__(256) void scan3_kernel(
    int* __restrict__ row, const int* __restrict__ bsum, int* __restrict__ cursor)
{
    int n = blockIdx.x * 256 + threadIdx.x;
    if (n >= NN) return;
    int r = row[n] + bsum[blockIdx.x];
    row[n] = r;
    cursor[n] = r;
    if (n == 0) row[NN] = EE;
}

// ---------------------------------------------------------------------------
// K_B: blocks [0, PAIR_BLOCKS) run iteration-0 edge update (needs log_b from
// K_A only); the rest run fill (needs cursor from scan3 only). The ~140us
// atomic-latency-bound fill hides under the edge compute.
// ---------------------------------------------------------------------------
__global__ __launch_bounds__(256) void k_edge0_fill(
    const int* __restrict__ ei, const float* __restrict__ T,
    const float* __restrict__ log_b, float* __restrict__ msg,
    int* __restrict__ cursor, int* __restrict__ eid)
{
    __shared__ float Hs[NC * NC];
    if (blockIdx.x < PAIR_BLOCKS) {
        stage_H(T, Hs, threadIdx.x);
        int e = blockIdx.x * 256 + threadIdx.x;
        if (e < MU) edge_body<1>(e, ei, log_b, msg, Hs);
    } else {
        int e = (blockIdx.x - PAIR_BLOCKS) * 256 + threadIdx.x;
        if (e < EE) eid[atomicAdd(&cursor[ei[EE + e]], 1)] = e;
    }
}

// ---------------------------------------------------------------------------
// steady-state edge kernel (iterations 1..4)
// ---------------------------------------------------------------------------
__global__ __launch_bounds__(256) void edge_kernel(
    const int* __restrict__ ei, const float* __restrict__ T,
    const float* __restrict__ log_b, float* __restrict__ msg)
{
    __shared__ float Hs[NC * NC];
    stage_H(T, Hs, threadIdx.x);
    int e = blockIdx.x * 256 + threadIdx.x;
    if (e < MU) edge_body<0>(e, ei, log_b, msg, Hs);
}

// ---------------------------------------------------------------------------
// node kernel: gather incoming msg rows via eid, sum + log_b0, normalize.
// ---------------------------------------------------------------------------
template <int LAST>
__global__ __launch_bounds__(256) void node_kernel(
    const int* __restrict__ row, const int* __restrict__ eid,
    const float* __restrict__ msg, const float* __restrict__ log_b0,
    float* __restrict__ log_b, float* __restrict__ out)
{
    int n = blockIdx.x * 256 + threadIdx.x;
    if (n >= NN) return;

    float a[NC];
    load_row16(log_b0 + (size_t)n * PAD, a);

    int r0 = row[n], r1 = row[n + 1];
    for (int s = r0; s < r1; ++s) {
        int e = eid[s];
        float t[NC];
        load_row8(msg + (size_t)e * MPAD, t);
#pragma unroll
        for (int c = 0; c < NC; ++c) a[c] += t[c];
    }

    float m = a[0];
#pragma unroll
    for (int c = 1; c < NC; ++c) m = fmaxf(m, a[c]);
    float s = 0.f;
#pragma unroll
    for (int c = 0; c < NC; ++c) s += __expf(a[c] - m);
    float lse = m + __logf(s);

    if (LAST) {
#pragma unroll
        for (int c = 0; c < NC; ++c) out[(size_t)n * NC + c] = a[c] - lse;
    } else {
        size_t o = (size_t)n * PAD;
#pragma unroll
        for (int c = 0; c < NC; ++c) log_b[o + c] = a[c] - lse;
    }
}

// ---------------------------------------------------------------------------
extern "C" void kernel_launch(void* const* d_in, const int* in_sizes, int n_in,
                              void* d_out, int out_size, void* d_ws, size_t ws_size,
                              hipStream_t stream)
{
    const float* x  = (const float*)d_in[0];
    const int*   ei = (const int*)d_in[1];
    // d_in[2] = rv — structure known (rv[e] = e +/- MU), not needed.
    const float* W  = (const float*)d_in[3];
    const float* b  = (const float*)d_in[4];
    const float* T  = (const float*)d_in[5];
    float* out = (float*)d_out;

    // ---- workspace layout, total ~84 MB ----
    float* ws      = (float*)d_ws;
    float* log_b0  = ws;                          // NN*PAD       6.4 MB
    float* log_b   = log_b0 + (size_t)NN * PAD;   // NN*PAD       6.4 MB
    float* msg     = log_b  + (size_t)NN * PAD;   // EE*MPAD     64.0 MB
    int*   eid     = (int*)(msg + (size_t)EE * MPAD); // EE       6.4 MB
    int*   deg     = eid + EE;                    // NN (doubles as cursor)
    int*   row     = deg + NN;                    // NN+16
    int*   bsum    = row + NN + 16;               // 512

    // zero deg (count accumulates into it)
    hipMemsetAsync(deg, 0, (size_t)NN * sizeof(int), stream);

    // K_A: transform || count  (independent; disjoint outputs)
    k_transform_count<<<NODE_BLOCKS + EDGE_BLOCKS, 256, 0, stream>>>(
        x, W, b, ei, log_b0, log_b, deg);

    // scans: deg -> row (exclusive prefix), cursor(=deg) = row
    scan1_kernel<<<NODE_BLOCKS, 256, 0, stream>>>(deg, row, bsum);
    scan2_kernel<<<1, 512, 0, stream>>>(bsum, NODE_BLOCKS);
    scan3_kernel<<<NODE_BLOCKS, 256, 0, stream>>>(row, bsum, deg);  // deg -> cursor

    // K_B: iteration-0 edge update || fill (independent; disjoint outputs)
    k_edge0_fill<<<PAIR_BLOCKS + EDGE_BLOCKS, 256, 0, stream>>>(
        ei, T, log_b, msg, deg, eid);

    node_kernel<0><<<NODE_BLOCKS, 256, 0, stream>>>(row, eid, msg, log_b0, log_b, out);

    // iterations 1..4
    for (int it = 1; it < 5; ++it) {
        edge_kernel<<<PAIR_BLOCKS, 256, 0, stream>>>(ei, T, log_b, msg);
        if (it < 4)
            node_kernel<0><<<NODE_BLOCKS, 256, 0, stream>>>(row, eid, msg, log_b0, log_b, out);
        else
            node_kernel<1><<<NODE_BLOCKS, 256, 0, stream>>>(row, eid, msg, log_b0, log_b, out);
    }
}

// Round 11
// 612.615 us; speedup vs baseline: 1.1933x; 1.1933x over previous
//
#include <hip/hip_runtime.h>
#include <math.h>

#define NN 100000      // nodes
#define DIN 128        // input features
#define NC 10          // classes
#define PAD 16         // node-array row stride (floats) -> 64B rows (1 cache line)
#define MPAD 10        // msg row stride (floats) -> 40B rows (8B aligned)
#define MU 800000      // undirected edge pairs
#define EE (2 * MU)    // directed edges

#define NODE_BLOCKS ((NN + 255) / 256)   // 391
#define PAIR_BLOCKS ((MU + 255) / 256)   // 3125
#define EDGE_BLOCKS ((EE + 255) / 256)   // 6250

// ---------- load/store 10 floats, 16B-aligned row (node arrays) ------------
__device__ __forceinline__ void load_row16(const float* __restrict__ p, float* r) {
    float4 v0 = *reinterpret_cast<const float4*>(p);
    float4 v1 = *reinterpret_cast<const float4*>(p + 4);
    float2 v2 = *reinterpret_cast<const float2*>(p + 8);
    r[0]=v0.x; r[1]=v0.y; r[2]=v0.z; r[3]=v0.w;
    r[4]=v1.x; r[5]=v1.y; r[6]=v1.z; r[7]=v1.w;
    r[8]=v2.x; r[9]=v2.y;
}
// ---------- load/store 10 floats, 8B-aligned row (msg array) ---------------
__device__ __forceinline__ void load_row8(const float* __restrict__ p, float* r) {
#pragma unroll
    for (int i = 0; i < 5; ++i) {
        float2 v = *reinterpret_cast<const float2*>(p + 2 * i);
        r[2 * i] = v.x; r[2 * i + 1] = v.y;
    }
}
__device__ __forceinline__ void store_row8(float* __restrict__ p, const float* r) {
#pragma unroll
    for (int i = 0; i < 5; ++i)
        *reinterpret_cast<float2*>(p + 2 * i) = make_float2(r[2 * i], r[2 * i + 1]);
}

// ---------- shared device bodies -------------------------------------------
__device__ __forceinline__ void transform_body(
    int n, int tid, const float* __restrict__ x, const float* __restrict__ W,
    const float* __restrict__ b, float* __restrict__ log_b0,
    float* __restrict__ log_b, float* Ws, float* bs)
{
    for (int i = tid; i < DIN * NC; i += 256) Ws[i] = W[i];
    if (tid < NC) bs[tid] = b[tid];
    __syncthreads();
    if (n >= NN) return;

    float acc[NC];
#pragma unroll
    for (int c = 0; c < NC; ++c) acc[c] = bs[c];

    const float4* xr = reinterpret_cast<const float4*>(x + (size_t)n * DIN);
#pragma unroll 4
    for (int k4 = 0; k4 < DIN / 4; ++k4) {
        float4 xv = xr[k4];
#pragma unroll
        for (int c = 0; c < NC; ++c) {
            acc[c] = fmaf(xv.x, Ws[(k4 * 4 + 0) * NC + c], acc[c]);
            acc[c] = fmaf(xv.y, Ws[(k4 * 4 + 1) * NC + c], acc[c]);
            acc[c] = fmaf(xv.z, Ws[(k4 * 4 + 2) * NC + c], acc[c]);
            acc[c] = fmaf(xv.w, Ws[(k4 * 4 + 3) * NC + c], acc[c]);
        }
    }
    float m = acc[0];
#pragma unroll
    for (int c = 1; c < NC; ++c) m = fmaxf(m, acc[c]);
    float s = 0.f;
#pragma unroll
    for (int c = 0; c < NC; ++c) s += __expf(acc[c] - m);
    float lse = m + __logf(s);

    size_t o = (size_t)n * PAD;
#pragma unroll
    for (int c = 0; c < NC; ++c) {
        float v = acc[c] - lse;
        log_b0[o + c] = v;
        log_b [o + c] = v;
    }
}

template <int FIRST>
__device__ __forceinline__ void edge_body(
    int e, const int* __restrict__ ei, const float* __restrict__ log_b,
    float* __restrict__ msg, const float* Hs)
{
    int u = ei[e];          // directed edge e:    u -> v
    int v = ei[EE + e];     // directed edge e+MU: v -> u

    float* muv = msg + (size_t)e * MPAD;
    float* mvu = msg + (size_t)(e + MU) * MPAD;

    float lbu[NC], lbv[NC];
    load_row16(log_b + (size_t)u * PAD, lbu);
    load_row16(log_b + (size_t)v * PAD, lbv);

    float v_uv[NC], v_vu[NC];
    if (FIRST) {
#pragma unroll
        for (int c = 0; c < NC; ++c) { v_uv[c] = lbu[c]; v_vu[c] = lbv[c]; }
    } else {
        float mo_uv[NC], mo_vu[NC];
        load_row8(muv, mo_uv);
        load_row8(mvu, mo_vu);
#pragma unroll
        for (int c = 0; c < NC; ++c) {
            v_uv[c] = lbu[c] - mo_vu[c];   // u->v subtracts reverse (v->u)
            v_vu[c] = lbv[c] - mo_uv[c];
        }
    }

    float m_uv = v_uv[0], m_vu = v_vu[0];
#pragma unroll
    for (int c = 1; c < NC; ++c) {
        m_uv = fmaxf(m_uv, v_uv[c]);
        m_vu = fmaxf(m_vu, v_vu[c]);
    }
    float p_uv[NC], p_vu[NC];
#pragma unroll
    for (int c = 0; c < NC; ++c) {
        p_uv[c] = __expf(v_uv[c] - m_uv);
        p_vu[c] = __expf(v_vu[c] - m_vu);
    }
    float q_uv[NC], q_vu[NC];
#pragma unroll
    for (int c = 0; c < NC; ++c) { q_uv[c] = 0.f; q_vu[c] = 0.f; }
#pragma unroll
    for (int c1 = 0; c1 < NC; ++c1) {
        float a = p_uv[c1], bb = p_vu[c1];
#pragma unroll
        for (int c2 = 0; c2 < NC; ++c2) {
            float h = Hs[c1 * NC + c2];      // shared by both directions (CSE)
            q_uv[c2] = fmaf(a, h, q_uv[c2]);
            q_vu[c2] = fmaf(bb, h, q_vu[c2]);
        }
    }
    float Q_uv = 0.f, Q_vu = 0.f;
#pragma unroll
    for (int c = 0; c < NC; ++c) { Q_uv += q_uv[c]; Q_vu += q_vu[c]; }
    float lQ_uv = __logf(Q_uv), lQ_vu = __logf(Q_vu);

    float nm_uv[NC], nm_vu[NC];
#pragma unroll
    for (int c = 0; c < NC; ++c) {
        nm_uv[c] = __logf(q_uv[c]) - lQ_uv;
        nm_vu[c] = __logf(q_vu[c]) - lQ_vu;
    }
    store_row8(muv, nm_uv);
    store_row8(mvu, nm_vu);
}

__device__ __forceinline__ void stage_H(const float* __restrict__ T, float* Hs, int tid)
{
    if (tid < NC * NC) {
        int i = tid / NC, j = tid % NC;
        float d2 = 0.f;
#pragma unroll
        for (int k = 0; k < NC; ++k) {
            float d = T[i * NC + k] - T[j * NC + k];
            d2 = fmaf(d, d, d2);
        }
        Hs[tid] = __expf(-d2);
    }
    __syncthreads();
}

// ---------------------------------------------------------------------------
// K_A: blocks [0, NODE_BLOCKS) run transform; the rest run count WITH rank
// capture: rank[e] = old count. This is the ONLY atomic pass in the whole
// launch — fill becomes pure arithmetic. deg pre-zeroed by hipMemsetAsync.
// ---------------------------------------------------------------------------
__global__ __launch_bounds__(256) void k_transform_count(
    const float* __restrict__ x, const float* __restrict__ W,
    const float* __restrict__ b, const int* __restrict__ ei,
    float* __restrict__ log_b0, float* __restrict__ log_b,
    int* __restrict__ deg, int* __restrict__ rank)
{
    __shared__ float Ws[DIN * NC];
    __shared__ float bs[NC];
    if (blockIdx.x < NODE_BLOCKS) {
        int n = blockIdx.x * 256 + threadIdx.x;
        transform_body(n, threadIdx.x, x, W, b, log_b0, log_b, Ws, bs);
    } else {
        int e = (blockIdx.x - NODE_BLOCKS) * 256 + threadIdx.x;
        if (e < EE) rank[e] = atomicAdd(&deg[ei[EE + e]], 1);
    }
}

// ---------------------------------------------------------------------------
// scans
// ---------------------------------------------------------------------------
__global__ __launch_bounds__(256) void scan1_kernel(
    const int* __restrict__ deg, int* __restrict__ row, int* __restrict__ bsum)
{
    __shared__ int tmp[256];
    int t = threadIdx.x;
    int n = blockIdx.x * 256 + t;
    int val = (n < NN) ? deg[n] : 0;
    tmp[t] = val;
    __syncthreads();
#pragma unroll
    for (int off = 1; off < 256; off <<= 1) {
        int v = (t >= off) ? tmp[t - off] : 0;
        __syncthreads();
        tmp[t] += v;
        __syncthreads();
    }
    if (n < NN) row[n] = tmp[t] - val;      // exclusive within block
    if (t == 255) bsum[blockIdx.x] = tmp[t];
}

__global__ __launch_bounds__(512) void scan2_kernel(int* __restrict__ bsum, int nb)
{
    __shared__ int tmp[512];
    int t = threadIdx.x;
    tmp[t] = (t < nb) ? bsum[t] : 0;
    __syncthreads();
#pragma unroll
    for (int off = 1; off < 512; off <<= 1) {
        int v = (t >= off) ? tmp[t - off] : 0;
        __syncthreads();
        tmp[t] += v;
        __syncthreads();
    }
    if (t < nb) bsum[t] = (t == 0) ? 0 : tmp[t - 1];   // exclusive
}

// row[n] += bsum[block]; row[NN] = EE
__global__ __launch_bounds__(256) void scan3_kernel(
    int* __restrict__ row, const int* __restrict__ bsum)
{
    int n = blockIdx.x * 256 + threadIdx.x;
    if (n >= NN) return;
    row[n] = row[n] + bsum[blockIdx.x];
    if (n == 0) row[NN] = EE;
}

// ---------------------------------------------------------------------------
// fill (ATOMIC-FREE): eid[row[dst[e]] + rank[e]] = e.
// Coalesced reads of ei/rank; row gather is L2-hot (400KB); eid writes are
// scattered but plain stores (no RMW round-trip).
// ---------------------------------------------------------------------------
__global__ __launch_bounds__(256) void fill_kernel(
    const int* __restrict__ ei, const int* __restrict__ row,
    const int* __restrict__ rank, int* __restrict__ eid)
{
    int e = blockIdx.x * 256 + threadIdx.x;
    if (e >= EE) return;
    eid[row[ei[EE + e]] + rank[e]] = e;
}

// ---------------------------------------------------------------------------
// edge kernel (iterations 0..4); FIRST=1 skips msg read (uniform init cancels)
// ---------------------------------------------------------------------------
template <int FIRST>
__global__ __launch_bounds__(256) void edge_kernel(
    const int* __restrict__ ei, const float* __restrict__ T,
    const float* __restrict__ log_b, float* __restrict__ msg)
{
    __shared__ float Hs[NC * NC];
    stage_H(T, Hs, threadIdx.x);
    int e = blockIdx.x * 256 + threadIdx.x;
    if (e < MU) edge_body<FIRST>(e, ei, log_b, msg, Hs);
}

// ---------------------------------------------------------------------------
// node kernel: gather incoming msg rows via eid, sum + log_b0, normalize.
// ---------------------------------------------------------------------------
template <int LAST>
__global__ __launch_bounds__(256) void node_kernel(
    const int* __restrict__ row, const int* __restrict__ eid,
    const float* __restrict__ msg, const float* __restrict__ log_b0,
    float* __restrict__ log_b, float* __restrict__ out)
{
    int n = blockIdx.x * 256 + threadIdx.x;
    if (n >= NN) return;

    float a[NC];
    load_row16(log_b0 + (size_t)n * PAD, a);

    int r0 = row[n], r1 = row[n + 1];
    for (int s = r0; s < r1; ++s) {
        int e = eid[s];
        float t[NC];
        load_row8(msg + (size_t)e * MPAD, t);
#pragma unroll
        for (int c = 0; c < NC; ++c) a[c] += t[c];
    }

    float m = a[0];
#pragma unroll
    for (int c = 1; c < NC; ++c) m = fmaxf(m, a[c]);
    float s = 0.f;
#pragma unroll
    for (int c = 0; c < NC; ++c) s += __expf(a[c] - m);
    float lse = m + __logf(s);

    if (LAST) {
#pragma unroll
        for (int c = 0; c < NC; ++c) out[(size_t)n * NC + c] = a[c] - lse;
    } else {
        size_t o = (size_t)n * PAD;
#pragma unroll
        for (int c = 0; c < NC; ++c) log_b[o + c] = a[c] - lse;
    }
}

// ---------------------------------------------------------------------------
extern "C" void kernel_launch(void* const* d_in, const int* in_sizes, int n_in,
                              void* d_out, int out_size, void* d_ws, size_t ws_size,
                              hipStream_t stream)
{
    const float* x  = (const float*)d_in[0];
    const int*   ei = (const int*)d_in[1];
    // d_in[2] = rv — structure known (rv[e] = e +/- MU), not needed.
    const float* W  = (const float*)d_in[3];
    const float* b  = (const float*)d_in[4];
    const float* T  = (const float*)d_in[5];
    float* out = (float*)d_out;

    // ---- workspace layout, total ~84 MB ----
    float* ws      = (float*)d_ws;
    float* log_b0  = ws;                          // NN*PAD       6.4 MB
    float* log_b   = log_b0 + (size_t)NN * PAD;   // NN*PAD       6.4 MB
    float* msg     = log_b  + (size_t)NN * PAD;   // EE*MPAD     64.0 MB
    int*   eid     = (int*)(msg + (size_t)EE * MPAD); // EE       6.4 MB
    int*   deg     = eid + EE;                    // NN
    int*   row     = deg + NN;                    // NN+16
    int*   bsum    = row + NN + 16;               // 512
    // rank[e] ALIASES msg's first 6.4MB: fill (reads rank) completes before
    // edge_kernel<1> (first msg write) on the same stream -> no conflict.
    int*   rank    = (int*)msg;

    // zero deg (count accumulates into it)
    hipMemsetAsync(deg, 0, (size_t)NN * sizeof(int), stream);

    // K_A: transform || count+rank  (the only atomic pass)
    k_transform_count<<<NODE_BLOCKS + EDGE_BLOCKS, 256, 0, stream>>>(
        x, W, b, ei, log_b0, log_b, deg, rank);

    // scans: deg -> row (exclusive prefix)
    scan1_kernel<<<NODE_BLOCKS, 256, 0, stream>>>(deg, row, bsum);
    scan2_kernel<<<1, 512, 0, stream>>>(bsum, NODE_BLOCKS);
    scan3_kernel<<<NODE_BLOCKS, 256, 0, stream>>>(row, bsum);

    // atomic-free fill
    fill_kernel<<<EDGE_BLOCKS, 256, 0, stream>>>(ei, row, rank, eid);

    // iteration 0 (uniform old messages cancel -> no msg read)
    edge_kernel<1><<<PAIR_BLOCKS, 256, 0, stream>>>(ei, T, log_b, msg);
    node_kernel<0><<<NODE_BLOCKS, 256, 0, stream>>>(row, eid, msg, log_b0, log_b, out);

    // iterations 1..4
    for (int it = 1; it < 5; ++it) {
        edge_kernel<0><<<PAIR_BLOCKS, 256, 0, stream>>>(ei, T, log_b, msg);
        if (it < 4)
            node_kernel<0><<<NODE_BLOCKS, 256, 0, stream>>>(row, eid, msg, log_b0, log_b, out);
        else
            node_kernel<1><<<NODE_BLOCKS, 256, 0, stream>>>(row, eid, msg, log_b0, log_b, out);
    }
}

// Round 14
// 550.011 us; speedup vs baseline: 1.3291x; 1.1138x over previous
//
#include <hip/hip_runtime.h>
#include <hip/hip_fp16.h>
#include <math.h>

#define NN 100000      // nodes
#define DIN 128        // input features
#define NC 10          // classes
#define PAD 16         // node-array row stride (floats) -> 64B rows (1 cache line)
#define MPADH 12       // msg row stride (halves) -> 24B rows (8B aligned)
#define MU 800000      // undirected edge pairs
#define EE (2 * MU)    // directed edges

#define NODE_BLOCKS ((NN + 255) / 256)   // 391
#define PAIR_BLOCKS ((MU + 255) / 256)   // 3125
#define EDGE_BLOCKS ((EE + 255) / 256)   // 6250

// ---------- load/store 10 floats, 16B-aligned row (node arrays) ------------
__device__ __forceinline__ void load_row16(const float* __restrict__ p, float* r) {
    float4 v0 = *reinterpret_cast<const float4*>(p);
    float4 v1 = *reinterpret_cast<const float4*>(p + 4);
    float2 v2 = *reinterpret_cast<const float2*>(p + 8);
    r[0]=v0.x; r[1]=v0.y; r[2]=v0.z; r[3]=v0.w;
    r[4]=v1.x; r[5]=v1.y; r[6]=v1.z; r[7]=v1.w;
    r[8]=v2.x; r[9]=v2.y;
}

// ---------- fp16 msg rows: 10 halves in a 24B (12-half) row ----------------
__device__ __forceinline__ float h2_as_f(__half2 h) {
    union { __half2 h; float f; } u; u.h = h; return u.f;
}
__device__ __forceinline__ __half2 f_as_h2(float f) {
    union { float f; __half2 h; } u; u.f = f; return u.h;
}
__device__ __forceinline__ void load_rowh(const __half* __restrict__ p, float* r) {
    float2 w0 = *reinterpret_cast<const float2*>(p);      // halves 0-3
    float2 w1 = *reinterpret_cast<const float2*>(p + 4);  // halves 4-7
    float  w2 = *reinterpret_cast<const float*>(p + 8);   // halves 8-9
    float2 t;
    t = __half22float2(f_as_h2(w0.x)); r[0]=t.x; r[1]=t.y;
    t = __half22float2(f_as_h2(w0.y)); r[2]=t.x; r[3]=t.y;
    t = __half22float2(f_as_h2(w1.x)); r[4]=t.x; r[5]=t.y;
    t = __half22float2(f_as_h2(w1.y)); r[6]=t.x; r[7]=t.y;
    t = __half22float2(f_as_h2(w2));   r[8]=t.x; r[9]=t.y;
}
__device__ __forceinline__ void store_rowh(__half* __restrict__ p, const float* r) {
    float2 w0, w1; float w2;
    w0.x = h2_as_f(__floats2half2_rn(r[0], r[1]));
    w0.y = h2_as_f(__floats2half2_rn(r[2], r[3]));
    w1.x = h2_as_f(__floats2half2_rn(r[4], r[5]));
    w1.y = h2_as_f(__floats2half2_rn(r[6], r[7]));
    w2   = h2_as_f(__floats2half2_rn(r[8], r[9]));
    *reinterpret_cast<float2*>(p)     = w0;
    *reinterpret_cast<float2*>(p + 4) = w1;
    *reinterpret_cast<float*>(p + 8)  = w2;
}

// ---------- shared device bodies -------------------------------------------
__device__ __forceinline__ void transform_body(
    int n, int tid, const float* __restrict__ x, const float* __restrict__ W,
    const float* __restrict__ b, float* __restrict__ log_b0,
    float* __restrict__ log_b, float* Ws, float* bs)
{
    for (int i = tid; i < DIN * NC; i += 256) Ws[i] = W[i];
    if (tid < NC) bs[tid] = b[tid];
    __syncthreads();
    if (n >= NN) return;

    float acc[NC];
#pragma unroll
    for (int c = 0; c < NC; ++c) acc[c] = bs[c];

    const float4* xr = reinterpret_cast<const float4*>(x + (size_t)n * DIN);
#pragma unroll 4
    for (int k4 = 0; k4 < DIN / 4; ++k4) {
        float4 xv = xr[k4];
#pragma unroll
        for (int c = 0; c < NC; ++c) {
            acc[c] = fmaf(xv.x, Ws[(k4 * 4 + 0) * NC + c], acc[c]);
            acc[c] = fmaf(xv.y, Ws[(k4 * 4 + 1) * NC + c], acc[c]);
            acc[c] = fmaf(xv.z, Ws[(k4 * 4 + 2) * NC + c], acc[c]);
            acc[c] = fmaf(xv.w, Ws[(k4 * 4 + 3) * NC + c], acc[c]);
        }
    }
    float m = acc[0];
#pragma unroll
    for (int c = 1; c < NC; ++c) m = fmaxf(m, acc[c]);
    float s = 0.f;
#pragma unroll
    for (int c = 0; c < NC; ++c) s += __expf(acc[c] - m);
    float lse = m + __logf(s);

    size_t o = (size_t)n * PAD;
#pragma unroll
    for (int c = 0; c < NC; ++c) {
        float v = acc[c] - lse;
        log_b0[o + c] = v;
        log_b [o + c] = v;
    }
}

template <int FIRST>
__device__ __forceinline__ void edge_body(
    int e, const int* __restrict__ ei, const float* __restrict__ log_b,
    __half* __restrict__ msg, const float* Hs)
{
    int u = ei[e];          // directed edge e:    u -> v
    int v = ei[EE + e];     // directed edge e+MU: v -> u

    __half* muv = msg + (size_t)e * MPADH;
    __half* mvu = msg + (size_t)(e + MU) * MPADH;

    float lbu[NC], lbv[NC];
    load_row16(log_b + (size_t)u * PAD, lbu);
    load_row16(log_b + (size_t)v * PAD, lbv);

    float v_uv[NC], v_vu[NC];
    if (FIRST) {
#pragma unroll
        for (int c = 0; c < NC; ++c) { v_uv[c] = lbu[c]; v_vu[c] = lbv[c]; }
    } else {
        float mo_uv[NC], mo_vu[NC];
        load_rowh(muv, mo_uv);
        load_rowh(mvu, mo_vu);
#pragma unroll
        for (int c = 0; c < NC; ++c) {
            v_uv[c] = lbu[c] - mo_vu[c];   // u->v subtracts reverse (v->u)
            v_vu[c] = lbv[c] - mo_uv[c];
        }
    }

    float m_uv = v_uv[0], m_vu = v_vu[0];
#pragma unroll
    for (int c = 1; c < NC; ++c) {
        m_uv = fmaxf(m_uv, v_uv[c]);
        m_vu = fmaxf(m_vu, v_vu[c]);
    }
    float p_uv[NC], p_vu[NC];
#pragma unroll
    for (int c = 0; c < NC; ++c) {
        p_uv[c] = __expf(v_uv[c] - m_uv);
        p_vu[c] = __expf(v_vu[c] - m_vu);
    }
    float q_uv[NC], q_vu[NC];
#pragma unroll
    for (int c = 0; c < NC; ++c) { q_uv[c] = 0.f; q_vu[c] = 0.f; }
#pragma unroll
    for (int c1 = 0; c1 < NC; ++c1) {
        float a = p_uv[c1], bb = p_vu[c1];
#pragma unroll
        for (int c2 = 0; c2 < NC; ++c2) {
            float h = Hs[c1 * NC + c2];      // shared by both directions (CSE)
            q_uv[c2] = fmaf(a, h, q_uv[c2]);
            q_vu[c2] = fmaf(bb, h, q_vu[c2]);
        }
    }
    float Q_uv = 0.f, Q_vu = 0.f;
#pragma unroll
    for (int c = 0; c < NC; ++c) { Q_uv += q_uv[c]; Q_vu += q_vu[c]; }
    float lQ_uv = __logf(Q_uv), lQ_vu = __logf(Q_vu);

    float nm_uv[NC], nm_vu[NC];
#pragma unroll
    for (int c = 0; c < NC; ++c) {
        nm_uv[c] = __logf(q_uv[c]) - lQ_uv;
        nm_vu[c] = __logf(q_vu[c]) - lQ_vu;
    }
    store_rowh(muv, nm_uv);
    store_rowh(mvu, nm_vu);
}

__device__ __forceinline__ void stage_H(const float* __restrict__ T, float* Hs, int tid)
{
    if (tid < NC * NC) {
        int i = tid / NC, j = tid % NC;
        float d2 = 0.f;
#pragma unroll
        for (int k = 0; k < NC; ++k) {
            float d = T[i * NC + k] - T[j * NC + k];
            d2 = fmaf(d, d, d2);
        }
        Hs[tid] = __expf(-d2);
    }
    __syncthreads();
}

// ---------------------------------------------------------------------------
// K_A: blocks [0, NODE_BLOCKS) run transform; the rest run count WITH rank
// capture: rank[e] = old count (the only atomic pass; fill is arithmetic).
// ---------------------------------------------------------------------------
__global__ __launch_bounds__(256) void k_transform_count(
    const float* __restrict__ x, const float* __restrict__ W,
    const float* __restrict__ b, const int* __restrict__ ei,
    float* __restrict__ log_b0, float* __restrict__ log_b,
    int* __restrict__ deg, int* __restrict__ rank)
{
    __shared__ float Ws[DIN * NC];
    __shared__ float bs[NC];
    if (blockIdx.x < NODE_BLOCKS) {
        int n = blockIdx.x * 256 + threadIdx.x;
        transform_body(n, threadIdx.x, x, W, b, log_b0, log_b, Ws, bs);
    } else {
        int e = (blockIdx.x - NODE_BLOCKS) * 256 + threadIdx.x;
        if (e < EE) rank[e] = atomicAdd(&deg[ei[EE + e]], 1);
    }
}

// ---------------------------------------------------------------------------
// scans
// ---------------------------------------------------------------------------
__global__ __launch_bounds__(256) void scan1_kernel(
    const int* __restrict__ deg, int* __restrict__ row, int* __restrict__ bsum)
{
    __shared__ int tmp[256];
    int t = threadIdx.x;
    int n = blockIdx.x * 256 + t;
    int val = (n < NN) ? deg[n] : 0;
    tmp[t] = val;
    __syncthreads();
#pragma unroll
    for (int off = 1; off < 256; off <<= 1) {
        int v = (t >= off) ? tmp[t - off] : 0;
        __syncthreads();
        tmp[t] += v;
        __syncthreads();
    }
    if (n < NN) row[n] = tmp[t] - val;      // exclusive within block
    if (t == 255) bsum[blockIdx.x] = tmp[t];
}

__global__ __launch_bounds__(512) void scan2_kernel(int* __restrict__ bsum, int nb)
{
    __shared__ int tmp[512];
    int t = threadIdx.x;
    tmp[t] = (t < nb) ? bsum[t] : 0;
    __syncthreads();
#pragma unroll
    for (int off = 1; off < 512; off <<= 1) {
        int v = (t >= off) ? tmp[t - off] : 0;
        __syncthreads();
        tmp[t] += v;
        __syncthreads();
    }
    if (t < nb) bsum[t] = (t == 0) ? 0 : tmp[t - 1];   // exclusive
}

// row[n] += bsum[block]; row[NN] = EE
__global__ __launch_bounds__(256) void scan3_kernel(
    int* __restrict__ row, const int* __restrict__ bsum)
{
    int n = blockIdx.x * 256 + threadIdx.x;
    if (n >= NN) return;
    row[n] = row[n] + bsum[blockIdx.x];
    if (n == 0) row[NN] = EE;
}

// ---------------------------------------------------------------------------
// fill (atomic-free): eid[row[dst[e]] + rank[e]] = e.
// ---------------------------------------------------------------------------
__global__ __launch_bounds__(256) void fill_kernel(
    const int* __restrict__ ei, const int* __restrict__ row,
    const int* __restrict__ rank, int* __restrict__ eid)
{
    int e = blockIdx.x * 256 + threadIdx.x;
    if (e >= EE) return;
    eid[row[ei[EE + e]] + rank[e]] = e;
}

// ---------------------------------------------------------------------------
// edge kernel (iterations 0..4); FIRST=1 skips msg read (uniform init cancels)
// ---------------------------------------------------------------------------
template <int FIRST>
__global__ __launch_bounds__(256) void edge_kernel(
    const int* __restrict__ ei, const float* __restrict__ T,
    const float* __restrict__ log_b, __half* __restrict__ msg)
{
    __shared__ float Hs[NC * NC];
    stage_H(T, Hs, threadIdx.x);
    int e = blockIdx.x * 256 + threadIdx.x;
    if (e < MU) edge_body<FIRST>(e, ei, log_b, msg, Hs);
}

// ---------------------------------------------------------------------------
// node kernel: gather incoming msg rows via eid, sum + log_b0, normalize.
// ---------------------------------------------------------------------------
template <int LAST>
__global__ __launch_bounds__(256) void node_kernel(
    const int* __restrict__ row, const int* __restrict__ eid,
    const __half* __restrict__ msg, const float* __restrict__ log_b0,
    float* __restrict__ log_b, float* __restrict__ out)
{
    int n = blockIdx.x * 256 + threadIdx.x;
    if (n >= NN) return;

    float a[NC];
    load_row16(log_b0 + (size_t)n * PAD, a);

    int r0 = row[n], r1 = row[n + 1];
    for (int s = r0; s < r1; ++s) {
        int e = eid[s];
        float t[NC];
        load_rowh(msg + (size_t)e * MPADH, t);
#pragma unroll
        for (int c = 0; c < NC; ++c) a[c] += t[c];
    }

    float m = a[0];
#pragma unroll
    for (int c = 1; c < NC; ++c) m = fmaxf(m, a[c]);
    float s = 0.f;
#pragma unroll
    for (int c = 0; c < NC; ++c) s += __expf(a[c] - m);
    float lse = m + __logf(s);

    if (LAST) {
#pragma unroll
        for (int c = 0; c < NC; ++c) out[(size_t)n * NC + c] = a[c] - lse;
    } else {
        size_t o = (size_t)n * PAD;
#pragma unroll
        for (int c = 0; c < NC; ++c) log_b[o + c] = a[c] - lse;
    }
}

// ---------------------------------------------------------------------------
extern "C" void kernel_launch(void* const* d_in, const int* in_sizes, int n_in,
                              void* d_out, int out_size, void* d_ws, size_t ws_size,
                              hipStream_t stream)
{
    const float* x  = (const float*)d_in[0];
    const int*   ei = (const int*)d_in[1];
    // d_in[2] = rv — structure known (rv[e] = e +/- MU), not needed.
    const float* W  = (const float*)d_in[3];
    const float* b  = (const float*)d_in[4];
    const float* T  = (const float*)d_in[5];
    float* out = (float*)d_out;

    // ---- workspace layout, total ~58 MB ----
    float*  ws      = (float*)d_ws;
    float*  log_b0  = ws;                          // NN*PAD        6.4 MB
    float*  log_b   = log_b0 + (size_t)NN * PAD;   // NN*PAD        6.4 MB
    __half* msg     = (__half*)(log_b + (size_t)NN * PAD); // EE*MPADH*2B = 38.4 MB
    int*    eid     = (int*)(msg + (size_t)EE * MPADH);    // EE     6.4 MB
    int*    deg     = eid + EE;                    // NN
    int*    row     = deg + NN;                    // NN+16
    int*    bsum    = row + NN + 16;               // 512
    // rank[e] ALIASES msg's first 6.4MB: fill (reads rank) completes before
    // edge_kernel<1> (first msg write) on the same stream -> no conflict.
    int*    rank    = (int*)msg;

    // zero deg (count accumulates into it)
    hipMemsetAsync(deg, 0, (size_t)NN * sizeof(int), stream);

    // K_A: transform || count+rank  (the only atomic pass)
    k_transform_count<<<NODE_BLOCKS + EDGE_BLOCKS, 256, 0, stream>>>(
        x, W, b, ei, log_b0, log_b, deg, rank);

    // scans: deg -> row (exclusive prefix)
    scan1_kernel<<<NODE_BLOCKS, 256, 0, stream>>>(deg, row, bsum);
    scan2_kernel<<<1, 512, 0, stream>>>(bsum, NODE_BLOCKS);
    scan3_kernel<<<NODE_BLOCKS, 256, 0, stream>>>(row, bsum);

    // atomic-free fill
    fill_kernel<<<EDGE_BLOCKS, 256, 0, stream>>>(ei, row, rank, eid);

    // iteration 0 (uniform old messages cancel -> no msg read)
    edge_kernel<1><<<PAIR_BLOCKS, 256, 0, stream>>>(ei, T, log_b, msg);
    node_kernel<0><<<NODE_BLOCKS, 256, 0, stream>>>(row, eid, msg, log_b0, log_b, out);

    // iterations 1..4
    for (int it = 1; it < 5; ++it) {
        edge_kernel<0><<<PAIR_BLOCKS, 256, 0, stream>>>(ei, T, log_b, msg);
        if (it < 4)
            node_kernel<0><<<NODE_BLOCKS, 256, 0, stream>>>(row, eid, msg, log_b0, log_b, out);
        else
            node_kernel<1><<<NODE_BLOCKS, 256, 0, stream>>>(row, eid, msg, log_b0, log_b, out);
    }
}